// Round 10
// baseline (354.748 us; speedup 1.0000x reference)
//
#include <hip/hip_runtime.h>
#include <hip/hip_bf16.h>

// Problem constants
#define BB   2
#define SS   4096
#define DD   256
#define HH   8
#define DKK  32
#define DFFC 1024
#define BS   (BB*SS)          // 8192 rows
#define MB   (1024*1024)

// softmax scale folded into q, log2 domain: 1/sqrt(32) * 1/ln(2)
#define SCALE2 (0.17677669529663689f * 1.4426950408889634f)

typedef float f32x4 __attribute__((ext_vector_type(4)));
typedef __bf16 bf16x8 __attribute__((ext_vector_type(8)));

// HW RNE f32->bf16: v_cvt_pk_bf16_f32 packs 2 conversions into 1 u32.
static __device__ __forceinline__ unsigned int cvtpk2(float lo, float hi) {
    unsigned int r;
    asm("v_cvt_pk_bf16_f32 %0, %1, %2" : "=v"(r) : "v"(lo), "v"(hi));
    return r;
}
static __device__ __forceinline__ unsigned short f2bf(float f) {
    return (unsigned short)cvtpk2(f, 0.0f);
}

// ---------------------------------------------------------------------------
// K0: one-shot WEIGHT conversions (src handled in-GEMM now).
// ---------------------------------------------------------------------------
__global__ __launch_bounds__(256) void convert_k(
    const float* __restrict__ Wq, const float* __restrict__ Wk,
    const float* __restrict__ Wv, const float* __restrict__ Wo,
    const float* __restrict__ W1, const float* __restrict__ W2,
    const float* __restrict__ bq, const float* __restrict__ bk,
    const float* __restrict__ bv,
    unsigned short* __restrict__ Wqkv_t, unsigned short* __restrict__ Wo_t,
    unsigned short* __restrict__ W1_t, unsigned short* __restrict__ W2_t,
    float* __restrict__ bqkv)
{
    int i = blockIdx.x * 256 + threadIdx.x;
    if (i < 196608) {                       // Wqkv_t [768][256]
        const int c = i >> 8, d = i & 255;
        const int which = c >> 8, h = (c >> 5) & 7, kk = c & 31;
        const float* W = which == 0 ? Wq : which == 1 ? Wk : Wv;
        Wqkv_t[i] = f2bf(W[h * 8192 + d * 32 + kk]);
        return;
    }
    i -= 196608;
    if (i < 65536) {                        // Wo_t [256][256]
        Wo_t[i] = f2bf(Wo[(i & 255) * 256 + (i >> 8)]);
        return;
    }
    i -= 65536;
    if (i < 262144) {                       // W1_t [1024][256]
        W1_t[i] = f2bf(W1[(i & 255) * 1024 + (i >> 8)]);
        return;
    }
    i -= 262144;
    if (i < 262144) {                       // W2_t [256][1024]
        W2_t[i] = f2bf(W2[(i & 1023) * 256 + (i >> 10)]);
        return;
    }
    i -= 262144;
    if (i < 768)
        bqkv[i] = (i < 256) ? bq[i] : (i < 512) ? bk[i - 256] : bv[i - 512];
}

// ---------------------------------------------------------------------------
// K1a: QKV GEMM, fp32 A (in-register cvt), BK=32, BM=128.
// C = src @ Wqkv_t^T + bqkv, scattered to qkv[which][B,H,S,32]; q *= SCALE2.
// ---------------------------------------------------------------------------
#define LDA 36   // padded LDS row stride (shorts) for BK=32

__global__ __launch_bounds__(256) void qkv_gemm_k(
    const float* __restrict__ A, const unsigned short* __restrict__ Bt,
    const float* __restrict__ bias, unsigned short* __restrict__ Cout)
{
    __shared__ unsigned short Al[128 * LDA];
    __shared__ unsigned short Bl[64 * LDA];

    const int tid  = threadIdx.x;
    const int w    = tid >> 6, lane = tid & 63;
    const int lq   = lane & 15, lk = lane >> 4;
    const int wr   = w >> 1,   wc = w & 1;
    const int m0   = blockIdx.y * 128, n0 = blockIdx.x * 64;

    const int arow = tid >> 1, ac = (tid & 1) * 16;   // 16 k-floats per thread
    const int brow = tid >> 2, bc = (tid & 3) * 8;
    const float* Ap = A + (size_t)(m0 + arow) * DD + ac;
    const unsigned short* Bp = Bt + (size_t)(n0 + brow) * DD + bc;

    f32x4 acc[4][2];
#pragma unroll
    for (int mi = 0; mi < 4; ++mi)
#pragma unroll
        for (int ni = 0; ni < 2; ++ni) acc[mi][ni] = (f32x4){0.f, 0.f, 0.f, 0.f};

    float4 f[4];
    int4 b0;
#pragma unroll
    for (int i = 0; i < 4; ++i) f[i] = *(const float4*)(Ap + i * 4);
    b0 = *(const int4*)(Bp);

    for (int k0 = 0; k0 < DD; k0 += 32) {
        int4 aA, aB;
        aA.x = (int)cvtpk2(f[0].x, f[0].y); aA.y = (int)cvtpk2(f[0].z, f[0].w);
        aA.z = (int)cvtpk2(f[1].x, f[1].y); aA.w = (int)cvtpk2(f[1].z, f[1].w);
        aB.x = (int)cvtpk2(f[2].x, f[2].y); aB.y = (int)cvtpk2(f[2].z, f[2].w);
        aB.z = (int)cvtpk2(f[3].x, f[3].y); aB.w = (int)cvtpk2(f[3].z, f[3].w);
        __syncthreads();
        *(int4*)&Al[arow * LDA + ac]     = aA;
        *(int4*)&Al[arow * LDA + ac + 8] = aB;
        *(int4*)&Bl[brow * LDA + bc]     = b0;
        __syncthreads();
        if (k0 + 32 < DD) {
#pragma unroll
            for (int i = 0; i < 4; ++i) f[i] = *(const float4*)(Ap + k0 + 32 + i * 4);
            b0 = *(const int4*)(Bp + k0 + 32);
        }

        bf16x8 bfrag[2];
#pragma unroll
        for (int ni = 0; ni < 2; ++ni)
            bfrag[ni] = *(const bf16x8*)&Bl[(wc * 32 + ni * 16 + lq) * LDA + lk * 8];
#pragma unroll
        for (int mi = 0; mi < 4; ++mi) {
            const bf16x8 afrag =
                *(const bf16x8*)&Al[(wr * 64 + mi * 16 + lq) * LDA + lk * 8];
#pragma unroll
            for (int ni = 0; ni < 2; ++ni)
                acc[mi][ni] = __builtin_amdgcn_mfma_f32_16x16x32_bf16(
                    afrag, bfrag[ni], acc[mi][ni], 0, 0, 0);
        }
    }

    // scatter epilogue
#pragma unroll
    for (int ni = 0; ni < 2; ++ni) {
        const int col = n0 + wc * 32 + ni * 16 + lq;
        const float bv_ = bias[col];
        const int which = col >> 8, h = (col >> 5) & 7, kk = col & 31;
#pragma unroll
        for (int mi = 0; mi < 4; ++mi) {
#pragma unroll
            for (int r = 0; r < 4; ++r) {
                const int row = m0 + wr * 64 + mi * 16 + lk * 4 + r;
                float val = acc[mi][ni][r] + bv_;
                if (which == 0) val *= SCALE2;
                const int b = row >> 12, s = row & (SS - 1);
                Cout[(size_t)which * 2097152 +
                     ((size_t)(b * 8 + h) * SS + s) * 32 + kk] = f2bf(val);
            }
        }
    }
}

// ---------------------------------------------------------------------------
// K1b: bf16 MFMA GEMM, BK=64.  C[M,N] = A[M,K] @ Bt[N,K]^T (+bias, epilogue)
// EPI 0: fp32 out = acc + bias + Rres     EPI 1: bf16 out = relu(acc + bias)
// ---------------------------------------------------------------------------
#define LDB 72   // padded LDS row stride (shorts) for BK=64

template <int EPI, int K, int BM>
__global__ __launch_bounds__(256) void mfma_gemm_k(
    const unsigned short* __restrict__ A,
    const unsigned short* __restrict__ Bt,
    const float* __restrict__ bias,
    const float* __restrict__ Rres,
    void* __restrict__ Cout, int N)
{
    constexpr int MI = BM / 32;
    __shared__ unsigned short Al[BM * LDB];
    __shared__ unsigned short Bl[64 * LDB];

    const int tid  = threadIdx.x;
    const int w    = tid >> 6, lane = tid & 63;
    const int lq   = lane & 15, lk = lane >> 4;
    const int wr   = w >> 1,   wc = w & 1;
    const int m0   = blockIdx.y * BM, n0 = blockIdx.x * 64;

    // staging roles (BK=64)
    const int arow = (BM == 128) ? (tid >> 1) : (tid >> 2);
    const int ac   = (BM == 128) ? ((tid & 1) * 32) : ((tid & 3) * 16);
    const int brow = tid >> 2, bc = (tid & 3) * 16;
    const unsigned short* Ap = A  + (size_t)(m0 + arow) * K + ac;
    const unsigned short* Bp = Bt + (size_t)(n0 + brow) * K + bc;

    f32x4 acc[MI][2];
#pragma unroll
    for (int mi = 0; mi < MI; ++mi)
#pragma unroll
        for (int ni = 0; ni < 2; ++ni) acc[mi][ni] = (f32x4){0.f, 0.f, 0.f, 0.f};

    constexpr int NA = (BM == 128) ? 4 : 2;
    int4 a[NA], b[2];
#pragma unroll
    for (int i = 0; i < NA; ++i) a[i] = *(const int4*)(Ap + i * 8);
    b[0] = *(const int4*)(Bp);
    b[1] = *(const int4*)(Bp + 8);

    for (int k0 = 0; k0 < K; k0 += 64) {
        __syncthreads();
#pragma unroll
        for (int i = 0; i < NA; ++i) *(int4*)&Al[arow * LDB + ac + i * 8] = a[i];
        *(int4*)&Bl[brow * LDB + bc]     = b[0];
        *(int4*)&Bl[brow * LDB + bc + 8] = b[1];
        __syncthreads();
        if (k0 + 64 < K) {
#pragma unroll
            for (int i = 0; i < NA; ++i) a[i] = *(const int4*)(Ap + k0 + 64 + i * 8);
            b[0] = *(const int4*)(Bp + k0 + 64);
            b[1] = *(const int4*)(Bp + k0 + 72);
        }

#pragma unroll
        for (int k2 = 0; k2 < 2; ++k2) {
            bf16x8 bfrag[2];
#pragma unroll
            for (int ni = 0; ni < 2; ++ni)
                bfrag[ni] = *(const bf16x8*)
                    &Bl[(wc * 32 + ni * 16 + lq) * LDB + k2 * 32 + lk * 8];
#pragma unroll
            for (int mi = 0; mi < MI; ++mi) {
                const bf16x8 afrag = *(const bf16x8*)
                    &Al[(wr * (BM / 2) + mi * 16 + lq) * LDB + k2 * 32 + lk * 8];
#pragma unroll
                for (int ni = 0; ni < 2; ++ni)
                    acc[mi][ni] = __builtin_amdgcn_mfma_f32_16x16x32_bf16(
                        afrag, bfrag[ni], acc[mi][ni], 0, 0, 0);
            }
        }
    }

#pragma unroll
    for (int ni = 0; ni < 2; ++ni) {
        const int col = n0 + wc * 32 + ni * 16 + lq;
        const float bv_ = bias[col];
#pragma unroll
        for (int mi = 0; mi < MI; ++mi) {
#pragma unroll
            for (int r = 0; r < 4; ++r) {
                const int row = m0 + wr * (BM / 2) + mi * 16 + lk * 4 + r;
                float val = acc[mi][ni][r] + bv_;
                if constexpr (EPI == 0) {
                    ((float*)Cout)[(size_t)row * N + col] =
                        val + Rres[(size_t)row * N + col];
                } else {
                    ((unsigned short*)Cout)[(size_t)row * N + col] =
                        f2bf(fmaxf(val, 0.f));
                }
            }
        }
    }
}

// ---------------------------------------------------------------------------
// K1c: V transpose  vb[BH][S][32] -> vbT[BH][32][S]   (global scalar gather,
// L1-served; coalesced b128 stores).  Grid 1024 x 256 thr.
// ---------------------------------------------------------------------------
__global__ __launch_bounds__(256) void vT_k(
    const unsigned short* __restrict__ vb, unsigned short* __restrict__ vbT)
{
    const int tid = threadIdx.x;
    const int bh  = blockIdx.x >> 6;
    const int s0  = (blockIdx.x & 63) * 64;
    const int kk  = tid >> 3;
    const int sp  = (tid & 7) * 8;
    const unsigned short* src = vb + ((size_t)bh * SS + s0 + sp) * DKK + kk;
    union { int4 i; unsigned short s[8]; } u;
#pragma unroll
    for (int j = 0; j < 8; ++j) u.s[j] = src[(size_t)j * DKK];
    *(int4*)(vbT + ((size_t)bh * DKK + kk) * SS + s0 + sp) = u.i;
}

// ---------------------------------------------------------------------------
// K2: MFMA flash attention.  4 waves x 16 q-rows; KV tile = 128.
// K staged permuted via m173 (linear LDS dest + inverse-permuted global src).
// V staged straight from pre-transposed vbT (2 b128 copies per thread).
// Row-sum via ones-MFMA (lacc).  Defer-max theta=8.  cvt_pk P-pack.
// ---------------------------------------------------------------------------
#define KVB 128
#define RK  40    // Kl row stride (shorts), 80 B
#define RVT 136   // Vt row stride (shorts), 272 B
#define RVP 136   // Pl row stride (shorts), 272 B

__global__ __launch_bounds__(256) void attn_mfma_k(
    const unsigned short* __restrict__ qb, const unsigned short* __restrict__ kb,
    const unsigned short* __restrict__ vbT, unsigned short* __restrict__ ctxb)
{
    __shared__ unsigned short Kl[KVB * RK];    // 10240 B
    __shared__ unsigned short Vt[32 * RVT];    //  8704 B  (Vt[dv][t])
    __shared__ unsigned short Pl[4][16 * RVP]; // 17408 B

    const int tid  = threadIdx.x;
    const int w    = tid >> 6;
    const int lane = tid & 63;
    const int lq   = lane & 15;
    const int lk   = lane >> 4;
    const int bh   = blockIdx.x;
    const int b    = bh >> 3;
    const int h    = bh & 7;
    const int q0   = blockIdx.y * 64;

    // K staging: linear LDS row rho; global row = inverse perm of krho.
    const int rho  = tid >> 1, ksel = tid & 1;
    const int kgt  = ((rho & 15) << 3) | (rho >> 4);
    // V staging: straight copy rows of vbT
    const int vdv  = tid >> 3, vsp = (tid & 7) * 16;

    const unsigned short* kg  = kb  + (size_t)bh * SS * DKK;
    const unsigned short* vtg = vbT + ((size_t)bh * DKK + vdv) * SS + vsp;

    union U16 { int4 i; bf16x8 b; unsigned short s[8]; };

    U16 uq;
    uq.i = *(const int4*)(qb + ((size_t)bh * SS + q0 + w * 16 + lq) * DKK + lk * 8);
    const bf16x8 aq = uq.b;

    const int4 onesi = make_int4(0x3F803F80, 0x3F803F80, 0x3F803F80, 0x3F803F80);
    const bf16x8 onesb = *(const bf16x8*)&onesi;

    float m_[4];
    f32x4 o0   = {0.f, 0.f, 0.f, 0.f};
    f32x4 o1   = {0.f, 0.f, 0.f, 0.f};
    f32x4 lacc = {0.f, 0.f, 0.f, 0.f};
#pragma unroll
    for (int r = 0; r < 4; ++r) m_[r] = -INFINITY;

    // preload tile 0
    int4 ka0 = *(const int4*)(kg + (size_t)kgt * DKK + ksel * 16);
    int4 ka1 = *(const int4*)(kg + (size_t)kgt * DKK + ksel * 16 + 8);
    int4 va0 = *(const int4*)(vtg);
    int4 va1 = *(const int4*)(vtg + 8);

    for (int t0 = 0; t0 < SS; t0 += KVB) {
        __syncthreads();
        *(int4*)&Kl[rho * RK + ksel * 16]     = ka0;
        *(int4*)&Kl[rho * RK + ksel * 16 + 8] = ka1;
        *(int4*)&Vt[vdv * RVT + vsp]          = va0;
        *(int4*)&Vt[vdv * RVT + vsp + 8]      = va1;
        __syncthreads();

        if (t0 + KVB < SS) {
            const unsigned short* kn = kg + (size_t)(t0 + KVB) * DKK;
            ka0 = *(const int4*)(kn + (size_t)kgt * DKK + ksel * 16);
            ka1 = *(const int4*)(kn + (size_t)kgt * DKK + ksel * 16 + 8);
            va0 = *(const int4*)(vtg + t0 + KVB);
            va1 = *(const int4*)(vtg + t0 + KVB + 8);
        }

        // QK^T: 8 mfma; acc[g] col lq = S[qrow][t = 8*lq + g]
        f32x4 acc[8];
#pragma unroll
        for (int g = 0; g < 8; ++g) {
            const bf16x8 bk_ = *(const bf16x8*)&Kl[(g * 16 + lq) * RK + lk * 8];
            acc[g] = __builtin_amdgcn_mfma_f32_16x16x32_bf16(
                aq, bk_, (f32x4){0.f, 0.f, 0.f, 0.f}, 0, 0, 0);
        }

        // row max
        float rm[4];
#pragma unroll
        for (int r = 0; r < 4; ++r) {
            float v = acc[0][r];
#pragma unroll
            for (int g = 1; g < 8; ++g) v = fmaxf(v, acc[g][r]);
            v = fmaxf(v, __shfl_xor(v, 1));
            v = fmaxf(v, __shfl_xor(v, 2));
            v = fmaxf(v, __shfl_xor(v, 4));
            v = fmaxf(v, __shfl_xor(v, 8));
            rm[r] = v;
        }
        // defer-max (theta=8, log2 domain)
        const bool grow = (rm[0] > m_[0] + 8.f) || (rm[1] > m_[1] + 8.f) ||
                          (rm[2] > m_[2] + 8.f) || (rm[3] > m_[3] + 8.f);
        if (__any(grow)) {
#pragma unroll
            for (int r = 0; r < 4; ++r) {
                const float mn = fmaxf(m_[r], rm[r]);
                const float c  = exp2f(m_[r] - mn);
                m_[r] = mn;
                lacc[r] *= c;
                o0[r] *= c;
                o1[r] *= c;
            }
        }
        // P = exp2(S - m); pack via cvt_pk -> one b128 per row
#pragma unroll
        for (int r = 0; r < 4; ++r) {
            float p[8];
#pragma unroll
            for (int g = 0; g < 8; ++g) p[g] = exp2f(acc[g][r] - m_[r]);
            int4 pi;
            pi.x = (int)cvtpk2(p[0], p[1]);
            pi.y = (int)cvtpk2(p[2], p[3]);
            pi.z = (int)cvtpk2(p[4], p[5]);
            pi.w = (int)cvtpk2(p[6], p[7]);
            *(int4*)&Pl[w][(lk * 4 + r) * RVP + lq * 8] = pi;
        }

        // PV + row-sum-by-MFMA
#pragma unroll
        for (int c2 = 0; c2 < 4; ++c2) {
            const bf16x8 pa = *(const bf16x8*)&Pl[w][lq * RVP + c2 * 32 + lk * 8];
            lacc = __builtin_amdgcn_mfma_f32_16x16x32_bf16(pa, onesb, lacc, 0, 0, 0);
            const bf16x8 v0 = *(const bf16x8*)&Vt[lq * RVT + c2 * 32 + lk * 8];
            o0 = __builtin_amdgcn_mfma_f32_16x16x32_bf16(pa, v0, o0, 0, 0, 0);
            const bf16x8 v1 = *(const bf16x8*)&Vt[(16 + lq) * RVT + c2 * 32 + lk * 8];
            o1 = __builtin_amdgcn_mfma_f32_16x16x32_bf16(pa, v1, o1, 0, 0, 0);
        }
    }

    // epilogue: lacc already holds full row sums
#pragma unroll
    for (int r = 0; r < 4; ++r) {
        const float inv = 1.0f / lacc[r];
        const size_t row = (size_t)b * SS + q0 + w * 16 + lk * 4 + r;
        unsigned short* cp = ctxb + row * (HH * DKK) + h * DKK;
        cp[lq]      = f2bf(o0[r] * inv);
        cp[16 + lq] = f2bf(o1[r] * inv);
    }
}

// ---------------------------------------------------------------------------
// K3: LayerNorm rows of 256; optional bf16 secondary output.
// ---------------------------------------------------------------------------
__global__ __launch_bounds__(256) void ln_k(
    const float* __restrict__ y, const float* __restrict__ g,
    const float* __restrict__ be, float* __restrict__ out,
    unsigned short* __restrict__ outb)
{
    const int tid = threadIdx.x;
    const size_t r = blockIdx.x;
    const float val = y[r * DD + tid];
    float s1 = val, s2 = val * val;
#pragma unroll
    for (int i = 1; i < 64; i <<= 1) {
        s1 += __shfl_xor(s1, i, 64);
        s2 += __shfl_xor(s2, i, 64);
    }
    __shared__ float ps1[4], ps2[4];
    const int w = tid >> 6, lane = tid & 63;
    if (lane == 0) { ps1[w] = s1; ps2[w] = s2; }
    __syncthreads();
    const float t1 = ps1[0] + ps1[1] + ps1[2] + ps1[3];
    const float t2 = ps2[0] + ps2[1] + ps2[2] + ps2[3];
    const float mean = t1 * (1.f / DD);
    const float var  = t2 * (1.f / DD) - mean * mean;
    const float rs   = rsqrtf(var + 1e-5f);
    const float res  = (val - mean) * rs * g[tid] + be[tid];
    out[r * DD + tid] = res;
    if (outb) outb[r * DD + tid] = f2bf(res);
}

// ---------------------------------------------------------------------------
extern "C" void kernel_launch(void* const* d_in, const int* in_sizes, int n_in,
                              void* d_out, int out_size, void* d_ws, size_t ws_size,
                              hipStream_t stream)
{
    const float* src  = (const float*)d_in[0];
    const float* Wq   = (const float*)d_in[1];
    const float* bq   = (const float*)d_in[2];
    const float* Wk   = (const float*)d_in[3];
    const float* bk   = (const float*)d_in[4];
    const float* Wv   = (const float*)d_in[5];
    const float* bv   = (const float*)d_in[6];
    const float* Wo   = (const float*)d_in[7];
    const float* bo   = (const float*)d_in[8];
    const float* ln1g = (const float*)d_in[9];
    const float* ln1b = (const float*)d_in[10];
    const float* W1   = (const float*)d_in[11];
    const float* b1   = (const float*)d_in[12];
    const float* W2   = (const float*)d_in[13];
    const float* b2   = (const float*)d_in[14];
    const float* ln2g = (const float*)d_in[15];
    const float* ln2b = (const float*)d_in[16];
    float* out = (float*)d_out;

    // Workspace (42 MB):
    //  [0,8M)    x fp32        [8M,12M)  xb bf16
    //  [12M,16M) qb  [16M,20M) kb  [20M,24M) vb  [24M,28M) vbT
    //  [28M,32M) ctxb bf16     [32M,40M) y1 fp32
    //  hh bf16 16MB = [12M,28M) (aliases qb..vbT, dead after attn)
    //  [40M,...) bf16 weights + bqkv
    char* wsb = (char*)d_ws;
    float*          x     = (float*)(wsb);
    unsigned short* xb    = (unsigned short*)(wsb + (size_t) 8 * MB);
    unsigned short* qb    = (unsigned short*)(wsb + (size_t)12 * MB);
    unsigned short* kb2   = (unsigned short*)(wsb + (size_t)16 * MB);
    unsigned short* vb2   = (unsigned short*)(wsb + (size_t)20 * MB);
    unsigned short* vbT   = (unsigned short*)(wsb + (size_t)24 * MB);
    unsigned short* ctxb  = (unsigned short*)(wsb + (size_t)28 * MB);
    float*          y1    = (float*)(wsb + (size_t)32 * MB);
    unsigned short* hh    = (unsigned short*)(wsb + (size_t)12 * MB);
    unsigned short* Wqkv_t= (unsigned short*)(wsb + (size_t)40 * MB);
    unsigned short* Wo_t  = (unsigned short*)(wsb + (size_t)40 * MB + 384 * 1024);
    unsigned short* W1_t  = (unsigned short*)(wsb + (size_t)40 * MB + 512 * 1024);
    unsigned short* W2_t  = (unsigned short*)(wsb + (size_t)40 * MB + 1024 * 1024);
    float*          bqkv  = (float*)(wsb + (size_t)40 * MB + 1536 * 1024);

    // 0. weight conversions (787,200 items)
    convert_k<<<3075, 256, 0, stream>>>(Wq, Wk, Wv, Wo, W1, W2, bq, bk, bv,
                                        Wqkv_t, Wo_t, W1_t, W2_t, bqkv);

    // 1. QKV: fp32 src @ Wqkv_t^T -> qb/kb/vb (scatter, q scaled)
    qkv_gemm_k<<<dim3(12, 64), 256, 0, stream>>>(src, Wqkv_t, bqkv, qb);

    // 1b. V transpose -> vbT[BH][32][S]
    vT_k<<<1024, 256, 0, stream>>>(vb2, vbT);

    // 2. flash attention -> ctxb bf16 [B,S,256]
    attn_mfma_k<<<dim3(BB * HH, SS / 64), 256, 0, stream>>>(qb, kb2, vbT, ctxb);

    // 3. ctxb @ Wo_t^T + bo + src -> y1 fp32
    mfma_gemm_k<0, DD, 64><<<dim3(4, 128), 256, 0, stream>>>(
        ctxb, Wo_t, bo, src, y1, DD);

    // 4. LN1: y1 -> x fp32 + xb bf16
    ln_k<<<BS, DD, 0, stream>>>(y1, ln1g, ln1b, x, xb);

    // 5. xb @ W1_t^T + b1, relu -> hh bf16
    mfma_gemm_k<1, DD, 128><<<dim3(16, 64), 256, 0, stream>>>(
        xb, W1_t, b1, nullptr, hh, DFFC);

    // 6. hh @ W2_t^T + b2 + x -> out fp32
    mfma_gemm_k<0, DFFC, 64><<<dim3(4, 128), 256, 0, stream>>>(
        hh, W2_t, b2, x, out, DD);

    // 7. LN2 in place
    ln_k<<<BS, DD, 0, stream>>>(out, ln2g, ln2b, out, nullptr);
}

// Round 11
// 333.812 us; speedup vs baseline: 1.0627x; 1.0627x over previous
//
#include <hip/hip_runtime.h>
#include <hip/hip_bf16.h>

// Problem constants
#define BB   2
#define SS   4096
#define DD   256
#define HH   8
#define DKK  32
#define DFFC 1024
#define BS   (BB*SS)          // 8192 rows
#define MB   (1024*1024)

// softmax scale folded into q, log2 domain: 1/sqrt(32) * 1/ln(2)
#define SCALE2 (0.17677669529663689f * 1.4426950408889634f)

typedef float f32x4 __attribute__((ext_vector_type(4)));
typedef __bf16 bf16x8 __attribute__((ext_vector_type(8)));

// HW RNE f32->bf16: v_cvt_pk_bf16_f32 packs 2 conversions into 1 u32.
static __device__ __forceinline__ unsigned int cvtpk2(float lo, float hi) {
    unsigned int r;
    asm("v_cvt_pk_bf16_f32 %0, %1, %2" : "=v"(r) : "v"(lo), "v"(hi));
    return r;
}
static __device__ __forceinline__ unsigned short f2bf(float f) {
    return (unsigned short)cvtpk2(f, 0.0f);
}

// ---------------------------------------------------------------------------
// K0: one-shot conversions (runs every launch; graph-safe).
// ---------------------------------------------------------------------------
__global__ __launch_bounds__(256) void convert_k(
    const float* __restrict__ src,
    const float* __restrict__ Wq, const float* __restrict__ Wk,
    const float* __restrict__ Wv, const float* __restrict__ Wo,
    const float* __restrict__ W1, const float* __restrict__ W2,
    const float* __restrict__ bq, const float* __restrict__ bk,
    const float* __restrict__ bv,
    unsigned short* __restrict__ srcb, unsigned short* __restrict__ Wqkv_t,
    unsigned short* __restrict__ Wo_t, unsigned short* __restrict__ W1_t,
    unsigned short* __restrict__ W2_t, float* __restrict__ bqkv)
{
    int idx = blockIdx.x * 256 + threadIdx.x;
    if (idx < 2097152) { srcb[idx] = f2bf(src[idx]); return; }
    int i = idx - 2097152;
    if (i < 196608) {                       // Wqkv_t [768][256]
        const int c = i >> 8, d = i & 255;
        const int which = c >> 8, h = (c >> 5) & 7, kk = c & 31;
        const float* W = which == 0 ? Wq : which == 1 ? Wk : Wv;
        Wqkv_t[i] = f2bf(W[h * 8192 + d * 32 + kk]);
        return;
    }
    i -= 196608;
    if (i < 65536) {                        // Wo_t [256][256]
        Wo_t[i] = f2bf(Wo[(i & 255) * 256 + (i >> 8)]);
        return;
    }
    i -= 65536;
    if (i < 262144) {                       // W1_t [1024][256]
        W1_t[i] = f2bf(W1[(i & 255) * 1024 + (i >> 8)]);
        return;
    }
    i -= 262144;
    if (i < 262144) {                       // W2_t [256][1024]
        W2_t[i] = f2bf(W2[(i & 1023) * 256 + (i >> 10)]);
        return;
    }
    i -= 262144;
    if (i < 768)
        bqkv[i] = (i < 256) ? bq[i] : (i < 512) ? bk[i - 256] : bv[i - 512];
}

// ---------------------------------------------------------------------------
// K1: bf16 MFMA GEMM, BK=32 (round-7 proven).  C = A @ Bt^T (+bias, epilogue)
// EPI 0: fp32 out = acc + bias + Rres
// EPI 1: bf16 out = relu(acc + bias)
// EPI 2: qkv scatter -> qkv[which][B,H,S,32]; q scaled; K rows PERMUTED:
//        within each 64-row group, K[t] stored at u = ((t&3)<<4)|(t>>2&15)
//        so attn's contiguous B-frag load gives col lq <-> t = 4*lq + g.
// ---------------------------------------------------------------------------
#define LDA 36   // padded LDS row stride (shorts) = 72 B

template <int EPI, int K, int BM>
__global__ __launch_bounds__(256) void mfma_gemm_k(
    const unsigned short* __restrict__ A,
    const unsigned short* __restrict__ Bt,
    const float* __restrict__ bias,
    const float* __restrict__ Rres,
    void* __restrict__ Cout, int N)
{
    constexpr int MI = BM / 32;
    __shared__ unsigned short Al[BM * LDA];
    __shared__ unsigned short Bl[64 * LDA];

    const int tid  = threadIdx.x;
    const int w    = tid >> 6, lane = tid & 63;
    const int lq   = lane & 15, lk = lane >> 4;
    const int wr   = w >> 1,   wc = w & 1;
    const int m0   = blockIdx.y * BM, n0 = blockIdx.x * 64;

    const int arow = (BM == 128) ? (tid >> 1) : (tid >> 2);
    const int ac   = (BM == 128) ? ((tid & 1) * 16) : ((tid & 3) * 8);
    const int brow = tid >> 2, bc = (tid & 3) * 8;
    const unsigned short* Ap = A  + (size_t)(m0 + arow) * K + ac;
    const unsigned short* Bp = Bt + (size_t)(n0 + brow) * K + bc;

    f32x4 acc[MI][2];
#pragma unroll
    for (int mi = 0; mi < MI; ++mi)
#pragma unroll
        for (int ni = 0; ni < 2; ++ni) acc[mi][ni] = (f32x4){0.f, 0.f, 0.f, 0.f};

    int4 a0, a1, b0;
    a0 = *(const int4*)(Ap);
    if constexpr (BM == 128) a1 = *(const int4*)(Ap + 8);
    b0 = *(const int4*)(Bp);

    for (int k0 = 0; k0 < K; k0 += 32) {
        __syncthreads();
        *(int4*)&Al[arow * LDA + ac] = a0;
        if constexpr (BM == 128) *(int4*)&Al[arow * LDA + ac + 8] = a1;
        *(int4*)&Bl[brow * LDA + bc] = b0;
        __syncthreads();
        if (k0 + 32 < K) {
            a0 = *(const int4*)(Ap + k0 + 32);
            if constexpr (BM == 128) a1 = *(const int4*)(Ap + k0 + 40);
            b0 = *(const int4*)(Bp + k0 + 32);
        }

        bf16x8 bfrag[2];
#pragma unroll
        for (int ni = 0; ni < 2; ++ni)
            bfrag[ni] = *(const bf16x8*)&Bl[(wc * 32 + ni * 16 + lq) * LDA + lk * 8];
#pragma unroll
        for (int mi = 0; mi < MI; ++mi) {
            const bf16x8 afrag =
                *(const bf16x8*)&Al[(wr * (BM / 2) + mi * 16 + lq) * LDA + lk * 8];
#pragma unroll
            for (int ni = 0; ni < 2; ++ni)
                acc[mi][ni] = __builtin_amdgcn_mfma_f32_16x16x32_bf16(
                    afrag, bfrag[ni], acc[mi][ni], 0, 0, 0);
        }
    }

#pragma unroll
    for (int ni = 0; ni < 2; ++ni) {
        const int col = n0 + wc * 32 + ni * 16 + lq;
        const float bv_ = bias[col];
#pragma unroll
        for (int mi = 0; mi < MI; ++mi) {
#pragma unroll
            for (int r = 0; r < 4; ++r) {
                const int row = m0 + wr * (BM / 2) + mi * 16 + lk * 4 + r;
                float val = acc[mi][ni][r] + bv_;
                if constexpr (EPI == 0) {
                    ((float*)Cout)[(size_t)row * N + col] =
                        val + Rres[(size_t)row * N + col];
                } else if constexpr (EPI == 1) {
                    ((unsigned short*)Cout)[(size_t)row * N + col] =
                        f2bf(fmaxf(val, 0.f));
                } else {
                    const int which = col >> 8, h = (col >> 5) & 7, kk = col & 31;
                    if (which == 0) val *= SCALE2;
                    const int b = row >> 12;
                    int s = row & (SS - 1);
                    if (which == 1)   // permute K rows within 64-groups
                        s = (s & ~63) | (((s & 3) << 4) | ((s & 63) >> 2));
                    ((unsigned short*)Cout)[(size_t)which * 2097152 +
                        ((size_t)(b * 8 + h) * SS + s) * 32 + kk] = f2bf(val);
                }
            }
        }
    }
}

// ---------------------------------------------------------------------------
// K1c: V transpose  vb[BH][S][32] -> vbT[BH][32][S]
// ---------------------------------------------------------------------------
__global__ __launch_bounds__(256) void vT_k(
    const unsigned short* __restrict__ vb, unsigned short* __restrict__ vbT)
{
    const int tid = threadIdx.x;
    const int bh  = blockIdx.x >> 6;
    const int s0  = (blockIdx.x & 63) * 64;
    const int kk  = tid >> 3;
    const int sp  = (tid & 7) * 8;
    const unsigned short* src = vb + ((size_t)bh * SS + s0 + sp) * DKK + kk;
    union { int4 i; unsigned short s[8]; } u;
#pragma unroll
    for (int j = 0; j < 8; ++j) u.s[j] = src[(size_t)j * DKK];
    *(int4*)(vbT + ((size_t)bh * DKK + kk) * SS + s0 + sp) = u.i;
}

// ---------------------------------------------------------------------------
// K2: MFMA flash attention, LDS-FREE K/V path.
// 4 waves x 16 q-rows; tile = 64 keys; NO __syncthreads in the loop.
// K B-frags load直接 from permuted kbP (contiguous 1KB/wave per mfma);
// V B-frags load from vbT global.  Only P round-trips through per-wave LDS
// (4x b64 write + 2x b128 read per tile).  Row-sum via ones-MFMA.
// Conditional rowmax: __any(lane-max > m+8) == old defer-max trigger.
// ---------------------------------------------------------------------------
#define RP 72   // Pl row stride (shorts) = 144 B (9 quads, odd -> balanced)

__global__ __launch_bounds__(256) void attn_mfma_k(
    const unsigned short* __restrict__ qb, const unsigned short* __restrict__ kbP,
    const unsigned short* __restrict__ vbT, unsigned short* __restrict__ ctxb)
{
    __shared__ unsigned short Pl[4][16 * RP];   // 9216 B total

    const int tid  = threadIdx.x;
    const int w    = tid >> 6;
    const int lane = tid & 63;
    const int lq   = lane & 15;
    const int lk   = lane >> 4;
    const int bh   = blockIdx.x;
    const int b    = bh >> 3;
    const int h    = bh & 7;
    const int q0   = blockIdx.y * 64;

    union U16 { int4 i; bf16x8 v; };

    U16 uq;
    uq.i = *(const int4*)(qb + ((size_t)bh * SS + q0 + w * 16 + lq) * DKK + lk * 8);
    const bf16x8 aq = uq.v;

    // per-lane global bases
    const unsigned short* kl0 = kbP + (size_t)bh * SS * DKK + (size_t)lq * DKK + lk * 8;
    const unsigned short* vl0 = vbT + (size_t)bh * DKK * SS + (size_t)lq * SS + lk * 8;

    const int4 onesi = make_int4(0x3F803F80, 0x3F803F80, 0x3F803F80, 0x3F803F80);
    U16 uo; uo.i = onesi;
    const bf16x8 onesb = uo.v;

    float m_[4];
    f32x4 o0   = {0.f, 0.f, 0.f, 0.f};
    f32x4 o1   = {0.f, 0.f, 0.f, 0.f};
    f32x4 lacc = {0.f, 0.f, 0.f, 0.f};
#pragma unroll
    for (int r = 0; r < 4; ++r) m_[r] = -INFINITY;

    for (int t0 = 0; t0 < SS; t0 += 64) {
        // issue all 8 global b128 loads up front (V latency hides under QK+softmax)
        U16 kf[4], vf[4];
#pragma unroll
        for (int g = 0; g < 4; ++g)
            kf[g].i = *(const int4*)(kl0 + (size_t)(t0 + g * 16) * DKK);
#pragma unroll
        for (int c2 = 0; c2 < 2; ++c2) {
            vf[c2 * 2 + 0].i = *(const int4*)(vl0 + t0 + c2 * 32);
            vf[c2 * 2 + 1].i = *(const int4*)(vl0 + (size_t)16 * SS + t0 + c2 * 32);
        }

        // QK^T: acc[g] col lq = S[qrow][t = t0 + 4*lq + g]  (kbP permutation)
        f32x4 acc[4];
#pragma unroll
        for (int g = 0; g < 4; ++g)
            acc[g] = __builtin_amdgcn_mfma_f32_16x16x32_bf16(
                aq, kf[g].v, (f32x4){0.f, 0.f, 0.f, 0.f}, 0, 0, 0);

        // per-lane max; cross-lane reduce + rescale only on growth tiles
        float rml[4];
#pragma unroll
        for (int r = 0; r < 4; ++r)
            rml[r] = fmaxf(fmaxf(acc[0][r], acc[1][r]),
                           fmaxf(acc[2][r], acc[3][r]));
        const bool grow = (rml[0] > m_[0] + 8.f) || (rml[1] > m_[1] + 8.f) ||
                          (rml[2] > m_[2] + 8.f) || (rml[3] > m_[3] + 8.f);
        if (__any(grow)) {
#pragma unroll
            for (int r = 0; r < 4; ++r) {
                float v = rml[r];
                v = fmaxf(v, __shfl_xor(v, 1));
                v = fmaxf(v, __shfl_xor(v, 2));
                v = fmaxf(v, __shfl_xor(v, 4));
                v = fmaxf(v, __shfl_xor(v, 8));
                const float mn = fmaxf(m_[r], v);
                const float c  = exp2f(m_[r] - mn);
                m_[r] = mn;
                lacc[r] *= c;
                o0[r] *= c;
                o1[r] *= c;
            }
        }

        // P = exp2(S - m): lane holds t = 4*lq + g, g=0..3 -> one b64 per row
#pragma unroll
        for (int r = 0; r < 4; ++r) {
            const float p0 = exp2f(acc[0][r] - m_[r]);
            const float p1 = exp2f(acc[1][r] - m_[r]);
            const float p2 = exp2f(acc[2][r] - m_[r]);
            const float p3 = exp2f(acc[3][r] - m_[r]);
            int2 pw;
            pw.x = (int)cvtpk2(p0, p1);
            pw.y = (int)cvtpk2(p2, p3);
            *(int2*)&Pl[w][(lk * 4 + r) * RP + lq * 4] = pw;
        }

        // PV + row-sum (per-wave LDS; in-order DS pipe, no barrier needed)
#pragma unroll
        for (int c2 = 0; c2 < 2; ++c2) {
            const bf16x8 pa = *(const bf16x8*)&Pl[w][lq * RP + c2 * 32 + lk * 8];
            lacc = __builtin_amdgcn_mfma_f32_16x16x32_bf16(pa, onesb, lacc, 0, 0, 0);
            o0 = __builtin_amdgcn_mfma_f32_16x16x32_bf16(pa, vf[c2*2+0].v, o0, 0, 0, 0);
            o1 = __builtin_amdgcn_mfma_f32_16x16x32_bf16(pa, vf[c2*2+1].v, o1, 0, 0, 0);
        }
    }

    // epilogue: lacc holds full row sums
#pragma unroll
    for (int r = 0; r < 4; ++r) {
        const float inv = 1.0f / lacc[r];
        const size_t row = (size_t)b * SS + q0 + w * 16 + lk * 4 + r;
        unsigned short* cp = ctxb + row * (HH * DKK) + h * DKK;
        cp[lq]      = f2bf(o0[r] * inv);
        cp[16 + lq] = f2bf(o1[r] * inv);
    }
}

// ---------------------------------------------------------------------------
// K3: LayerNorm rows of 256; optional bf16 secondary output.
// ---------------------------------------------------------------------------
__global__ __launch_bounds__(256) void ln_k(
    const float* __restrict__ y, const float* __restrict__ g,
    const float* __restrict__ be, float* __restrict__ out,
    unsigned short* __restrict__ outb)
{
    const int tid = threadIdx.x;
    const size_t r = blockIdx.x;
    const float val = y[r * DD + tid];
    float s1 = val, s2 = val * val;
#pragma unroll
    for (int i = 1; i < 64; i <<= 1) {
        s1 += __shfl_xor(s1, i, 64);
        s2 += __shfl_xor(s2, i, 64);
    }
    __shared__ float ps1[4], ps2[4];
    const int w = tid >> 6, lane = tid & 63;
    if (lane == 0) { ps1[w] = s1; ps2[w] = s2; }
    __syncthreads();
    const float t1 = ps1[0] + ps1[1] + ps1[2] + ps1[3];
    const float t2 = ps2[0] + ps2[1] + ps2[2] + ps2[3];
    const float mean = t1 * (1.f / DD);
    const float var  = t2 * (1.f / DD) - mean * mean;
    const float rs   = rsqrtf(var + 1e-5f);
    const float res  = (val - mean) * rs * g[tid] + be[tid];
    out[r * DD + tid] = res;
    if (outb) outb[r * DD + tid] = f2bf(res);
}

// ---------------------------------------------------------------------------
extern "C" void kernel_launch(void* const* d_in, const int* in_sizes, int n_in,
                              void* d_out, int out_size, void* d_ws, size_t ws_size,
                              hipStream_t stream)
{
    const float* src  = (const float*)d_in[0];
    const float* Wq   = (const float*)d_in[1];
    const float* bq   = (const float*)d_in[2];
    const float* Wk   = (const float*)d_in[3];
    const float* bk   = (const float*)d_in[4];
    const float* Wv   = (const float*)d_in[5];
    const float* bv   = (const float*)d_in[6];
    const float* Wo   = (const float*)d_in[7];
    const float* bo   = (const float*)d_in[8];
    const float* ln1g = (const float*)d_in[9];
    const float* ln1b = (const float*)d_in[10];
    const float* W1   = (const float*)d_in[11];
    const float* b1   = (const float*)d_in[12];
    const float* W2   = (const float*)d_in[13];
    const float* b2   = (const float*)d_in[14];
    const float* ln2g = (const float*)d_in[15];
    const float* ln2b = (const float*)d_in[16];
    float* out = (float*)d_out;

    // Workspace (~37.6 MB):
    //  [0,8M)   x fp32      [8M,12M)  xb bf16     [12M,16M) srcb bf16
    //  [16M,20M) qb         [20M,24M) kbP         [24M,28M) vb
    //  [28M,32M) vbT        [32M,36M) ctxb
    //  y1 fp32 8MB = [16M,24M)  (aliases qb/kbP, dead after attn)
    //  hh bf16 16MB = [20M,36M) (aliases kbP/vb/vbT/ctxb, dead after LN1)
    //  [36M,...) bf16 weights + bqkv
    char* wsb = (char*)d_ws;
    float*          x     = (float*)(wsb);
    unsigned short* xb    = (unsigned short*)(wsb + (size_t) 8 * MB);
    unsigned short* srcb  = (unsigned short*)(wsb + (size_t)12 * MB);
    unsigned short* qb    = (unsigned short*)(wsb + (size_t)16 * MB);
    unsigned short* kbP   = (unsigned short*)(wsb + (size_t)20 * MB);
    unsigned short* vb2   = (unsigned short*)(wsb + (size_t)24 * MB);
    unsigned short* vbT   = (unsigned short*)(wsb + (size_t)28 * MB);
    unsigned short* ctxb  = (unsigned short*)(wsb + (size_t)32 * MB);
    float*          y1    = (float*)(wsb + (size_t)16 * MB);
    unsigned short* hh    = (unsigned short*)(wsb + (size_t)20 * MB);
    unsigned short* Wqkv_t= (unsigned short*)(wsb + (size_t)36 * MB);
    unsigned short* Wo_t  = (unsigned short*)(wsb + (size_t)36 * MB + 384 * 1024);
    unsigned short* W1_t  = (unsigned short*)(wsb + (size_t)36 * MB + 512 * 1024);
    unsigned short* W2_t  = (unsigned short*)(wsb + (size_t)36 * MB + 1024 * 1024);
    float*          bqkv  = (float*)(wsb + (size_t)36 * MB + 1536 * 1024);

    // 0. conversions (2,884,352 items)
    convert_k<<<11267, 256, 0, stream>>>(src, Wq, Wk, Wv, Wo, W1, W2, bq, bk, bv,
                                         srcb, Wqkv_t, Wo_t, W1_t, W2_t, bqkv);

    // 1. QKV: srcb @ Wqkv_t^T -> qb / kbP (row-permuted) / vb
    mfma_gemm_k<2, DD, 128><<<dim3(12, 64), 256, 0, stream>>>(
        srcb, Wqkv_t, bqkv, nullptr, qb, 768);

    // 1b. V transpose -> vbT[BH][32][S]
    vT_k<<<1024, 256, 0, stream>>>(vb2, vbT);

    // 2. flash attention -> ctxb bf16 [B,S,256]
    attn_mfma_k<<<dim3(BB * HH, SS / 64), 256, 0, stream>>>(qb, kbP, vbT, ctxb);

    // 3. ctxb @ Wo_t^T + bo + src -> y1 fp32
    mfma_gemm_k<0, DD, 64><<<dim3(4, 128), 256, 0, stream>>>(
        ctxb, Wo_t, bo, src, y1, DD);

    // 4. LN1: y1 -> x fp32 + xb bf16
    ln_k<<<BS, DD, 0, stream>>>(y1, ln1g, ln1b, x, xb);

    // 5. xb @ W1_t^T + b1, relu -> hh bf16
    mfma_gemm_k<1, DD, 128><<<dim3(16, 64), 256, 0, stream>>>(
        xb, W1_t, b1, nullptr, hh, DFFC);

    // 6. hh @ W2_t^T + b2 + x -> out fp32
    mfma_gemm_k<0, DFFC, 64><<<dim3(4, 128), 256, 0, stream>>>(
        hh, W2_t, b2, x, out, DD);

    // 7. LN2 in place
    ln_k<<<BS, DD, 0, stream>>>(out, ln2g, ln2b, out, nullptr);
}